// Round 1
// 1307.549 us; speedup vs baseline: 1.1242x; 1.1242x over previous
//
#include <hip/hip_runtime.h>
#include <hip/hip_bf16.h>

#define DD    1024
#define NROWS 3072
#define NLAY  17
#define MS    20     // LDS row stride for 16x16 matrices (80B = 5*16B, keeps b128 alignment)

typedef __attribute__((ext_vector_type(8))) short short8;
typedef __attribute__((ext_vector_type(4))) float floatx4;

// ---------------------------------------------------------------- weight convert
// W0 (1M) ++ Ws (16M) fp32 -> bf16, 4 elems/thread
__global__ __launch_bounds__(256) void convw_kernel(const float* __restrict__ W0,
                                                    const float* __restrict__ Ws,
                                                    ushort* __restrict__ Wbf) {
  const size_t i4 = ((size_t)blockIdx.x * 256 + threadIdx.x) * 4;
  float4 v;
  if (i4 < 1048576) v = *(const float4*)(W0 + i4);
  else              v = *(const float4*)(Ws + (i4 - 1048576));
  union { __hip_bfloat16 h[4]; ushort u[4]; } pk;
  pk.h[0] = __float2bfloat16(v.x); pk.h[1] = __float2bfloat16(v.y);
  pk.h[2] = __float2bfloat16(v.z); pk.h[3] = __float2bfloat16(v.w);
  *(ushort4*)(Wbf + i4) = *(ushort4*)pk.u;
}

// ---------------------------------------------------------------- prep
// Build X0 rows (bf16): ch0/ch1 copy, ch2 = transpose of (16,64) -> (64,16)
__global__ __launch_bounds__(256) void prep_kernel(const float* __restrict__ Xin,
                                                   ushort* __restrict__ X0bf) {
  const int row = blockIdx.x;           // 0..3071  (= b*3 + c)
  const int c   = row % 3;
  const float* src = Xin + (size_t)row * DD;
  ushort* dst = X0bf + (size_t)row * DD;
  for (int t = threadIdx.x; t < DD; t += 256) {
    float v;
    if (c == 2) v = src[(t & 15) * 64 + (t >> 4)];
    else        v = src[t];
    __hip_bfloat16 h = __float2bfloat16(v);
    dst[t] = *(ushort*)&h;
  }
}

// ---------------------------------------------------------------- MFMA GEMM
// Y[m][e] = sum_d A[m][d] * W[e][d]   (A,W bf16 row-major, NT)
// fuse==1: Y = Xres + h * relu(dot + bias)   (Xres fp32)
// 128x128 tile, BK=32, 4 waves 2x2, each wave 4x4 mfma_f32_16x16x32_bf16
__global__ __launch_bounds__(256) void gemm_kernel(
    const ushort* __restrict__ Abf, const ushort* __restrict__ Wbf,
    const float* __restrict__ Xres, const float* __restrict__ bias,
    const float* __restrict__ hp, float* __restrict__ Y, int fuse)
{
  __shared__ __align__(16) ushort As[128 * 32];
  __shared__ __align__(16) ushort Bs[128 * 32];
  const int tid  = threadIdx.x;
  const int wave = tid >> 6, lane = tid & 63;
  const int bm = blockIdx.y * 128, bn = blockIdx.x * 128;

  // staging: wave w covers rows [q*64 + w*16, +16), lane -> (row=lane>>2, 16B col chunk=lane&3)
  const int srow = wave * 16 + (lane >> 2);
  const int scol = (lane & 3) * 8;                  // bf16 elements
  const ushort* ga0 = Abf + (size_t)(bm + srow) * DD + scol;
  const ushort* gb0 = Wbf + (size_t)(bn + srow) * DD + scol;

  const int wm0 = (wave >> 1) * 64, wn0 = (wave & 1) * 64;
  const int m = lane & 15, quad = lane >> 4;

  floatx4 acc[4][4] = {};

  for (int k0 = 0; k0 < DD; k0 += 32) {
    __syncthreads();                                // prev tile's reads done
#pragma unroll
    for (int q = 0; q < 2; ++q) {
      __builtin_amdgcn_global_load_lds(
          (const __attribute__((address_space(1))) unsigned int*)(ga0 + (size_t)q * 64 * DD + k0),
          (__attribute__((address_space(3))) unsigned int*)&As[(q * 64 + wave * 16) * 32],
          16, 0, 0);
      __builtin_amdgcn_global_load_lds(
          (const __attribute__((address_space(1))) unsigned int*)(gb0 + (size_t)q * 64 * DD + k0),
          (__attribute__((address_space(3))) unsigned int*)&Bs[(q * 64 + wave * 16) * 32],
          16, 0, 0);
    }
    __syncthreads();                                // staging visible

    short8 av[4], bv[4];
#pragma unroll
    for (int i = 0; i < 4; ++i)
      av[i] = *(const short8*)&As[(wm0 + i * 16 + m) * 32 + quad * 8];
#pragma unroll
    for (int j = 0; j < 4; ++j)
      bv[j] = *(const short8*)&Bs[(wn0 + j * 16 + m) * 32 + quad * 8];
#pragma unroll
    for (int i = 0; i < 4; ++i)
#pragma unroll
      for (int j = 0; j < 4; ++j)
        acc[i][j] = __builtin_amdgcn_mfma_f32_16x16x32_bf16(av[i], bv[j], acc[i][j], 0, 0, 0);
  }

  // epilogue: C layout col=lane&15, row=quad*4+reg
  const float h = fuse ? hp[0] : 0.0f;
#pragma unroll
  for (int i = 0; i < 4; ++i) {
#pragma unroll
    for (int r = 0; r < 4; ++r) {
      const int grow = bm + wm0 + i * 16 + quad * 4 + r;
      float* yr = Y + (size_t)grow * DD;
      const float* xr = Xres + (size_t)grow * DD;
#pragma unroll
      for (int j = 0; j < 4; ++j) {
        const int gcol = bn + wn0 + j * 16 + m;
        float d = acc[i][j][r];
        if (fuse) d = xr[gcol] + h * fmaxf(d + bias[gcol], 0.0f);
        yr[gcol] = d;
      }
    }
  }
}

// ---------------------------------------------------------------- projection
// One wave (64 threads) per block.
// Blocks 0..2047: one polar projection each (channels 0/2 rows).
// Blocks 2048..3071: channel-1 passthrough copy (Y -> X, + bf16 stage).
// polar(A) = A * (A^T A)^{-1/2}; Newton-Schulz on G scaled by |A|_F^2.
// Symmetry: Y0=G, Z0=I -> all iterates are polynomials in G => symmetric and
// commuting. Hence Z' = T*Z = Z*T, so both updates share one T-column read,
// and rows of Y/Z are contiguous b128 reads. Single-wave blocks make
// __syncthreads() near-free and in-place Y/Z update safe (lockstep order).
__global__ __launch_bounds__(64) void proj_kernel(
    const float* __restrict__ Yg, float* __restrict__ Xg,
    __hip_bfloat16* __restrict__ stage, int layer, int iters)
{
  __shared__ float At[16 * 68];
  __shared__ __align__(16) float Yb[16 * MS];
  __shared__ __align__(16) float Zb[16 * MS];
  __shared__ __align__(16) float Tb[16 * MS];

  const int lane = threadIdx.x;                  // 0..63

  if (blockIdx.x >= 2048) {                      // ---- channel-1 copy path
    const int b = blockIdx.x - 2048;             // 0..1023
    const int row = b * 3 + 1;
    const float* src = Yg + (size_t)row * DD + lane * 16;
    float* dst = Xg + (size_t)row * DD + lane * 16;
    float v[16];
#pragma unroll
    for (int q = 0; q < 4; ++q) {
      const float4 t4 = *(const float4*)(src + q * 4);
      v[q*4+0]=t4.x; v[q*4+1]=t4.y; v[q*4+2]=t4.z; v[q*4+3]=t4.w;
      *(float4*)(dst + q * 4) = t4;
    }
    union { __hip_bfloat16 hh[16]; uint4 u[2]; } pk;
#pragma unroll
    for (int j = 0; j < 16; ++j) pk.hh[j] = __float2bfloat16(v[j]);
    uint4* sd = (uint4*)(stage + ((size_t)layer * NROWS + row) * DD + lane * 16);
    sd[0] = pk.u[0]; sd[1] = pk.u[1];
    return;
  }

  const int p = blockIdx.x;              // 0..2047
  const int b = p >> 1;
  const int row = b * 3 + (p & 1) * 2;   // channel 0 or 2
  const float* src = Yg + (size_t)row * DD + lane * 16;

  // lane = row i of A(64x16); v = A[i][0..15]
  float v[16];
#pragma unroll
  for (int q = 0; q < 4; ++q) {
    const float4 t4 = *(const float4*)(src + q * 4);
    v[q*4+0]=t4.x; v[q*4+1]=t4.y; v[q*4+2]=t4.z; v[q*4+3]=t4.w;
  }
  float f2 = 0.f;
#pragma unroll
  for (int j = 0; j < 16; ++j) f2 += v[j] * v[j];
#pragma unroll
  for (int o = 32; o > 0; o >>= 1) f2 += __shfl_xor(f2, o, 64);
  const float s = rsqrtf(f2 + 1e-30f);
#pragma unroll
  for (int j = 0; j < 16; ++j) v[j] *= s;       // v = scaled A row

#pragma unroll
  for (int j = 0; j < 16; ++j) At[j * 68 + lane] = v[j];   // A^T, [16][68]
  __syncthreads();

  const int r  = lane >> 2;          // my output row  (0..15)
  const int c0 = (lane & 3) * 4;     // my 4-col block
  // G[r][c0..c0+3] = (sA)^T (sA)
  float g0=0.f, g1=0.f, g2=0.f, g3=0.f;
  for (int i0 = 0; i0 < 64; i0 += 4) {
    const float4 aj = *(const float4*)&At[r * 68 + i0];
    const float4 a0 = *(const float4*)&At[(c0+0) * 68 + i0];
    const float4 a1 = *(const float4*)&At[(c0+1) * 68 + i0];
    const float4 a2 = *(const float4*)&At[(c0+2) * 68 + i0];
    const float4 a3 = *(const float4*)&At[(c0+3) * 68 + i0];
    g0 += aj.x*a0.x + aj.y*a0.y + aj.z*a0.z + aj.w*a0.w;
    g1 += aj.x*a1.x + aj.y*a1.y + aj.z*a1.z + aj.w*a1.w;
    g2 += aj.x*a2.x + aj.y*a2.y + aj.z*a2.z + aj.w*a2.w;
    g3 += aj.x*a3.x + aj.y*a3.y + aj.z*a3.z + aj.w*a3.w;
  }
  *(float4*)&Yb[r * MS + c0] = make_float4(g0, g1, g2, g3);
  *(float4*)&Zb[r * MS + c0] = make_float4(r == c0+0 ? 1.f : 0.f,
                                           r == c0+1 ? 1.f : 0.f,
                                           r == c0+2 ? 1.f : 0.f,
                                           r == c0+3 ? 1.f : 0.f);
  __syncthreads();

  for (int it = 0; it < iters; ++it) {
    // load my Z row and Y row (contiguous, b128) -- Z is not written in phase 1,
    // so zr stays valid for phase 2.
    float zr[16], yr[16];
    {
      const float4 za = *(const float4*)&Zb[r * MS + 0];
      const float4 zb4 = *(const float4*)&Zb[r * MS + 4];
      const float4 zc = *(const float4*)&Zb[r * MS + 8];
      const float4 zd = *(const float4*)&Zb[r * MS + 12];
      zr[0]=za.x; zr[1]=za.y; zr[2]=za.z; zr[3]=za.w;
      zr[4]=zb4.x; zr[5]=zb4.y; zr[6]=zb4.z; zr[7]=zb4.w;
      zr[8]=zc.x; zr[9]=zc.y; zr[10]=zc.z; zr[11]=zc.w;
      zr[12]=zd.x; zr[13]=zd.y; zr[14]=zd.z; zr[15]=zd.w;
      const float4 ya = *(const float4*)&Yb[r * MS + 0];
      const float4 yb4 = *(const float4*)&Yb[r * MS + 4];
      const float4 yc = *(const float4*)&Yb[r * MS + 8];
      const float4 yd = *(const float4*)&Yb[r * MS + 12];
      yr[0]=ya.x; yr[1]=ya.y; yr[2]=ya.z; yr[3]=ya.w;
      yr[4]=yb4.x; yr[5]=yb4.y; yr[6]=yb4.z; yr[7]=yb4.w;
      yr[8]=yc.x; yr[9]=yc.y; yr[10]=yc.z; yr[11]=yc.w;
      yr[12]=yd.x; yr[13]=yd.y; yr[14]=yd.z; yr[15]=yd.w;
    }
    // T = 0.5*(3I - Z*Y)
    float p0=0.f, p1=0.f, p2=0.f, p3=0.f;
#pragma unroll
    for (int k = 0; k < 16; ++k) {
      const float4 y4 = *(const float4*)&Yb[k * MS + c0];
      p0 = fmaf(zr[k], y4.x, p0); p1 = fmaf(zr[k], y4.y, p1);
      p2 = fmaf(zr[k], y4.z, p2); p3 = fmaf(zr[k], y4.w, p3);
    }
    float4 tv;
    tv.x = 0.5f * ((r == c0+0 ? 3.f : 0.f) - p0);
    tv.y = 0.5f * ((r == c0+1 ? 3.f : 0.f) - p1);
    tv.z = 0.5f * ((r == c0+2 ? 3.f : 0.f) - p2);
    tv.w = 0.5f * ((r == c0+3 ? 3.f : 0.f) - p3);
    *(float4*)&Tb[r * MS + c0] = tv;
    __syncthreads();                         // T visible
    // Ynew = Y*T ; Znew = Z*T  (all iterates symmetric & commuting)
    float4 py = make_float4(0,0,0,0), pz = make_float4(0,0,0,0);
#pragma unroll
    for (int k = 0; k < 16; ++k) {
      const float4 t4 = *(const float4*)&Tb[k * MS + c0];
      py.x = fmaf(yr[k], t4.x, py.x); py.y = fmaf(yr[k], t4.y, py.y);
      py.z = fmaf(yr[k], t4.z, py.z); py.w = fmaf(yr[k], t4.w, py.w);
      pz.x = fmaf(zr[k], t4.x, pz.x); pz.y = fmaf(zr[k], t4.y, pz.y);
      pz.z = fmaf(zr[k], t4.z, pz.z); pz.w = fmaf(zr[k], t4.w, pz.w);
    }
    // in-place update: safe within a single wave (all reads precede writes
    // in the one lockstep instruction stream; LDS ops in-order per wave)
    *(float4*)&Yb[r * MS + c0] = py;
    *(float4*)&Zb[r * MS + c0] = pz;
    __syncthreads();                         // Y,Z visible for next iter
  }

  // Up[i][j] = sum_k (sA)[i][k] * Z[k][j]   (lane = row i)
  float up[16] = {};
#pragma unroll
  for (int k = 0; k < 16; ++k) {
    const float a = v[k];
#pragma unroll
    for (int j0 = 0; j0 < 16; j0 += 4) {
      const float4 z4 = *(const float4*)&Zb[k * MS + j0];  // uniform -> broadcast
      up[j0+0] = fmaf(a, z4.x, up[j0+0]);
      up[j0+1] = fmaf(a, z4.y, up[j0+1]);
      up[j0+2] = fmaf(a, z4.z, up[j0+2]);
      up[j0+3] = fmaf(a, z4.w, up[j0+3]);
    }
  }
  float* dst = Xg + (size_t)row * DD + lane * 16;
#pragma unroll
  for (int q = 0; q < 4; ++q)
    *(float4*)(dst + q*4) = make_float4(up[q*4], up[q*4+1], up[q*4+2], up[q*4+3]);
  union { __hip_bfloat16 hh[16]; uint4 u[2]; } pk;
#pragma unroll
  for (int j = 0; j < 16; ++j) pk.hh[j] = __float2bfloat16(up[j]);
  uint4* sd = (uint4*)(stage + ((size_t)layer * NROWS + row) * DD + lane * 16);
  sd[0] = pk.u[0]; sd[1] = pk.u[1];
}

// ---------------------------------------------------------------- transpose epilogue
// stage (l, row, d) bf16 -> out (row, d, l) fp32, coalesced both ways via LDS
__global__ __launch_bounds__(256) void transpose_kernel(
    const __hip_bfloat16* __restrict__ stage, float* __restrict__ outT)
{
  __shared__ float buf[256 * 18];
  const int row = blockIdx.y;          // 0..3071
  const int d0  = blockIdx.x * 256;    // 0,256,512,768
  const int t   = threadIdx.x;
  for (int l = 0; l < NLAY; ++l)
    buf[t * 18 + l] = __bfloat162float(stage[((size_t)l * NROWS + row) * DD + d0 + t]);
  __syncthreads();
  const size_t ob = (size_t)(row * DD + d0) * NLAY;
  for (int i = 0; i < NLAY; ++i) {
    const int idx = i * 256 + t;       // < 4352
    const int dd = idx / 17, ll = idx % 17;
    outT[ob + idx] = buf[dd * 18 + ll];
  }
}

// ---------------------------------------------------------------- classify
// Z = U @ S[:16,:16] @ V^T (64x64); logits = Z @ Wc^T + bc; softmax
__global__ __launch_bounds__(256) void classify_kernel(
    const float* __restrict__ X, const float* __restrict__ Wc,
    const float* __restrict__ bc, float* __restrict__ out)
{
  __shared__ float U[64*17], S[16*17], V[64*17], T[64*17];
  __shared__ float Z[4096];
  __shared__ float wsum[4][10];
  const int b = blockIdx.x, t = threadIdx.x;
  const float* x0 = X + (size_t)(b*3+0) * DD;
  const float* x1 = X + (size_t)(b*3+1) * DD;
  const float* x2 = X + (size_t)(b*3+2) * DD;
  for (int e = t; e < 1024; e += 256) {
    const int i = e >> 4, j = e & 15;
    U[i*17+j] = x0[e];
    V[i*17+j] = x2[e];
  }
  { const int i = t >> 4, j = t & 15; if (t < 256) S[i*17+j] = x1[i*16+j]; }
  __syncthreads();
  for (int e = t; e < 1024; e += 256) {     // T = U @ S
    const int i = e >> 4, j = e & 15;
    float a = 0.f;
    for (int k = 0; k < 16; ++k) a = fmaf(U[i*17+k], S[k*17+j], a);
    T[i*17+j] = a;
  }
  __syncthreads();
  for (int e = t; e < 4096; e += 256) {     // Z = T @ V^T
    const int i = e >> 6, j = e & 63;
    float a = 0.f;
    for (int k = 0; k < 16; ++k) a = fmaf(T[i*17+k], V[j*17+k], a);
    Z[e] = a;
  }
  __syncthreads();
  // logits: read Z once, 10 register accumulators, wave shuffle reduce, 1 barrier
  float part[10] = {};
  for (int e = t; e < 4096; e += 256) {
    const float z = Z[e];
#pragma unroll
    for (int n = 0; n < 10; ++n) part[n] = fmaf(z, Wc[(size_t)n * 4096 + e], part[n]);
  }
#pragma unroll
  for (int n = 0; n < 10; ++n) {
#pragma unroll
    for (int off = 32; off > 0; off >>= 1) part[n] += __shfl_xor(part[n], off, 64);
  }
  if ((t & 63) == 0) {
#pragma unroll
    for (int n = 0; n < 10; ++n) wsum[t >> 6][n] = part[n];
  }
  __syncthreads();
  if (t == 0) {
    float logits[10];
#pragma unroll
    for (int n = 0; n < 10; ++n)
      logits[n] = wsum[0][n] + wsum[1][n] + wsum[2][n] + wsum[3][n] + bc[n];
    float mx = logits[0];
    for (int n = 1; n < 10; ++n) mx = fmaxf(mx, logits[n]);
    float ex[10], sm = 0.f;
    for (int n = 0; n < 10; ++n) { ex[n] = expf(logits[n] - mx); sm += ex[n]; }
    const float inv = 1.f / sm;
    for (int n = 0; n < 10; ++n) {
      out[b*10 + n] = ex[n] * inv;          // X_predicted
      out[10240 + b*10 + n] = logits[n];    // X_classified
    }
  }
}

// ---------------------------------------------------------------- launch
extern "C" void kernel_launch(void* const* d_in, const int* in_sizes, int n_in,
                              void* d_out, int out_size, void* d_ws, size_t ws_size,
                              hipStream_t stream) {
  const float* Xin = (const float*)d_in[0];
  const float* hp  = (const float*)d_in[1];
  const float* W0  = (const float*)d_in[2];
  const float* Ws  = (const float*)d_in[3];
  const float* bs  = (const float*)d_in[4];
  const float* Wc  = (const float*)d_in[5];
  const float* bc  = (const float*)d_in[6];
  float* out = (float*)d_out;

  char* ws = (char*)d_ws;
  float* Xb = (float*)ws;                                   // 3072*1024 f32
  float* Yb = Xb + (size_t)NROWS * DD;                      // 3072*1024 f32
  __hip_bfloat16* stage =
      (__hip_bfloat16*)(ws + 2 * (size_t)NROWS * DD * 4);   // 17*3072*1024 bf16
  ushort* X0bf = (ushort*)(ws + 2 * (size_t)NROWS * DD * 4
                              + (size_t)NLAY * NROWS * DD * 2);   // 3072*1024 bf16
  ushort* Wbf  = X0bf + (size_t)NROWS * DD;                 // 17*1024*1024 bf16

  convw_kernel<<<17408, 256, 0, stream>>>(W0, Ws, Wbf);
  prep_kernel<<<NROWS, 256, 0, stream>>>(Xin, X0bf);

  // layer 0: Linear (no bias), then projection
  gemm_kernel<<<dim3(8, 24), 256, 0, stream>>>(X0bf, Wbf, Xb, bs, hp, Yb, 0);
  proj_kernel<<<3072, 64, 0, stream>>>(Yb, Xb, stage, 0, 16);

  for (int l = 0; l < 16; ++l) {
    gemm_kernel<<<dim3(8, 24), 256, 0, stream>>>(
        (const ushort*)(stage + (size_t)l * NROWS * DD),
        Wbf + (size_t)(l + 1) * DD * DD,
        Xb, bs + (size_t)l * DD, hp, Yb, 1);
    proj_kernel<<<3072, 64, 0, stream>>>(Yb, Xb, stage, l + 1, 12);
  }

  transpose_kernel<<<dim3(4, NROWS), 256, 0, stream>>>(stage, out + 20480);
  classify_kernel<<<1024, 256, 0, stream>>>(Xb, Wc, bc, out);
}

// Round 2
// 1069.010 us; speedup vs baseline: 1.3750x; 1.2231x over previous
//
#include <hip/hip_runtime.h>
#include <hip/hip_bf16.h>

#define DD    1024
#define NROWS 3072
#define NLAY  17
#define MS    20     // LDS row stride for 16x16 matrices (80B = 5*16B, keeps b128 alignment)

typedef __attribute__((ext_vector_type(8))) short short8;
typedef __attribute__((ext_vector_type(4))) float floatx4;

// ---------------------------------------------------------------- weight convert
// W0 (1M) ++ Ws (16M) fp32 -> bf16, 4 elems/thread
__global__ __launch_bounds__(256) void convw_kernel(const float* __restrict__ W0,
                                                    const float* __restrict__ Ws,
                                                    ushort* __restrict__ Wbf) {
  const size_t i4 = ((size_t)blockIdx.x * 256 + threadIdx.x) * 4;
  float4 v;
  if (i4 < 1048576) v = *(const float4*)(W0 + i4);
  else              v = *(const float4*)(Ws + (i4 - 1048576));
  union { __hip_bfloat16 h[4]; ushort u[4]; } pk;
  pk.h[0] = __float2bfloat16(v.x); pk.h[1] = __float2bfloat16(v.y);
  pk.h[2] = __float2bfloat16(v.z); pk.h[3] = __float2bfloat16(v.w);
  *(ushort4*)(Wbf + i4) = *(ushort4*)pk.u;
}

// ---------------------------------------------------------------- prep
// Build X0 rows (bf16): ch0/ch1 copy, ch2 = transpose of (16,64) -> (64,16)
__global__ __launch_bounds__(256) void prep_kernel(const float* __restrict__ Xin,
                                                   ushort* __restrict__ X0bf) {
  const int row = blockIdx.x;           // 0..3071  (= b*3 + c)
  const int c   = row % 3;
  const float* src = Xin + (size_t)row * DD;
  ushort* dst = X0bf + (size_t)row * DD;
  for (int t = threadIdx.x; t < DD; t += 256) {
    float v;
    if (c == 2) v = src[(t & 15) * 64 + (t >> 4)];
    else        v = src[t];
    __hip_bfloat16 h = __float2bfloat16(v);
    dst[t] = *(ushort*)&h;
  }
}

// ---------------------------------------------------------------- MFMA GEMM
// Y[m][e] = sum_d A[m][d] * W[e][d]   (A,W bf16 row-major, NT)
// fuse==1: Y = Xres + h * relu(dot + bias)   (Xres fp32)
// 128x64 tile (M x N), BK=32, 4 waves 2x2 (each 64x32), grid 384 blocks:
// full CU coverage (192-block 128x128 left 64 CUs idle, no latency overlap).
// XCD-chunked swizzle: blocks sharing an A-panel land on one XCD's L2.
__global__ __launch_bounds__(256) void gemm_kernel(
    const ushort* __restrict__ Abf, const ushort* __restrict__ Wbf,
    const float* __restrict__ Xres, const float* __restrict__ bias,
    const float* __restrict__ hp, float* __restrict__ Y, int fuse)
{
  __shared__ __align__(16) ushort As[128 * 32];
  __shared__ __align__(16) ushort Bs[64 * 32];
  const int tid  = threadIdx.x;
  const int wave = tid >> 6, lane = tid & 63;

  // bijective XCD swizzle (384 % 8 == 0): xcd chunk = id % 8, 48 blocks/chunk
  const int id = blockIdx.x;
  const int w  = (id & 7) * 48 + (id >> 3);
  const int bm = (w >> 4) * 128;        // 24 M-tiles
  const int bn = (w & 15) * 64;         // 16 N-tiles

  // staging: lane -> (row=lane>>2, 16B col chunk=lane&3)
  const int srow = wave * 16 + (lane >> 2);
  const int scol = (lane & 3) * 8;                  // bf16 elements
  const ushort* ga0 = Abf + (size_t)(bm + srow) * DD + scol;
  const ushort* gb0 = Wbf + (size_t)(bn + srow) * DD + scol;

  const int wm0 = (wave >> 1) * 64, wn0 = (wave & 1) * 32;
  const int m = lane & 15, quad = lane >> 4;

  floatx4 acc[4][2] = {};

  for (int k0 = 0; k0 < DD; k0 += 32) {
    __syncthreads();                                // prev tile's reads done
#pragma unroll
    for (int q = 0; q < 2; ++q) {
      __builtin_amdgcn_global_load_lds(
          (const __attribute__((address_space(1))) unsigned int*)(ga0 + (size_t)q * 64 * DD + k0),
          (__attribute__((address_space(3))) unsigned int*)&As[(q * 64 + wave * 16) * 32],
          16, 0, 0);
    }
    __builtin_amdgcn_global_load_lds(
        (const __attribute__((address_space(1))) unsigned int*)(gb0 + k0),
        (__attribute__((address_space(3))) unsigned int*)&Bs[(wave * 16) * 32],
        16, 0, 0);
    __syncthreads();                                // staging visible

    short8 av[4], bv[2];
#pragma unroll
    for (int i = 0; i < 4; ++i)
      av[i] = *(const short8*)&As[(wm0 + i * 16 + m) * 32 + quad * 8];
#pragma unroll
    for (int j = 0; j < 2; ++j)
      bv[j] = *(const short8*)&Bs[(wn0 + j * 16 + m) * 32 + quad * 8];
#pragma unroll
    for (int i = 0; i < 4; ++i)
#pragma unroll
      for (int j = 0; j < 2; ++j)
        acc[i][j] = __builtin_amdgcn_mfma_f32_16x16x32_bf16(av[i], bv[j], acc[i][j], 0, 0, 0);
  }

  // epilogue: C layout col=lane&15, row=quad*4+reg
  const float h = fuse ? hp[0] : 0.0f;
#pragma unroll
  for (int i = 0; i < 4; ++i) {
#pragma unroll
    for (int r = 0; r < 4; ++r) {
      const int grow = bm + wm0 + i * 16 + quad * 4 + r;
      float* yr = Y + (size_t)grow * DD;
      const float* xr = Xres + (size_t)grow * DD;
#pragma unroll
      for (int j = 0; j < 2; ++j) {
        const int gcol = bn + wn0 + j * 16 + m;
        float d = acc[i][j][r];
        if (fuse) d = xr[gcol] + h * fmaxf(d + bias[gcol], 0.0f);
        yr[gcol] = d;
      }
    }
  }
}

// ---------------------------------------------------------------- projection
// One wave (64 threads) per block.
// Blocks 0..2047: one polar projection each (channels 0/2 rows).
// Blocks 2048..3071: channel-1 passthrough copy (Y -> X, + bf16 stage).
// polar(A) = A * (A^T A)^{-1/2}; Newton-Schulz on G rescaled by ||G||_F:
// guarantees scaled eigenvalues <= 1 and ~4x larger floor than the old
// ||A||_F^2 scaling -> fewer climb iterations (13/9 instead of 16/12).
// G computed via 2x mfma_f32_16x16x32_bf16 (replaces an 80-b128-read loop);
// bf16 G error ~5e-4 in U, below the bf16 staging ulp already in absmax.
__global__ __launch_bounds__(64) void proj_kernel(
    const float* __restrict__ Yg, float* __restrict__ Xg,
    __hip_bfloat16* __restrict__ stage, int layer, int iters)
{
  __shared__ float At[16 * 68];
  __shared__ __align__(16) float Yb[16 * MS];
  __shared__ __align__(16) float Zb[16 * MS];
  __shared__ __align__(16) float Tb[16 * MS];

  const int lane = threadIdx.x;                  // 0..63

  if (blockIdx.x >= 2048) {                      // ---- channel-1 copy path
    const int b = blockIdx.x - 2048;             // 0..1023
    const int row = b * 3 + 1;
    const float* src = Yg + (size_t)row * DD + lane * 16;
    float* dst = Xg + (size_t)row * DD + lane * 16;
    float v[16];
#pragma unroll
    for (int q = 0; q < 4; ++q) {
      const float4 t4 = *(const float4*)(src + q * 4);
      v[q*4+0]=t4.x; v[q*4+1]=t4.y; v[q*4+2]=t4.z; v[q*4+3]=t4.w;
      *(float4*)(dst + q * 4) = t4;
    }
    union { __hip_bfloat16 hh[16]; uint4 u[2]; } pk;
#pragma unroll
    for (int j = 0; j < 16; ++j) pk.hh[j] = __float2bfloat16(v[j]);
    uint4* sd = (uint4*)(stage + ((size_t)layer * NROWS + row) * DD + lane * 16);
    sd[0] = pk.u[0]; sd[1] = pk.u[1];
    return;
  }

  const int p = blockIdx.x;              // 0..2047
  const int b = p >> 1;
  const int row = b * 3 + (p & 1) * 2;   // channel 0 or 2
  const float* src = Yg + (size_t)row * DD + lane * 16;

  // lane = row i of A(64x16); v = A[i][0..15]
  float v[16];
#pragma unroll
  for (int q = 0; q < 4; ++q) {
    const float4 t4 = *(const float4*)(src + q * 4);
    v[q*4+0]=t4.x; v[q*4+1]=t4.y; v[q*4+2]=t4.z; v[q*4+3]=t4.w;
  }
  float f2 = 0.f;
#pragma unroll
  for (int j = 0; j < 16; ++j) f2 += v[j] * v[j];
#pragma unroll
  for (int o = 32; o > 0; o >>= 1) f2 += __shfl_xor(f2, o, 64);
  const float s = rsqrtf(f2 + 1e-30f);
#pragma unroll
  for (int j = 0; j < 16; ++j) v[j] *= s;       // v = scaled A row

#pragma unroll
  for (int j = 0; j < 16; ++j) At[j * 68 + lane] = v[j];   // A^T, [16][68]
  __syncthreads();

  // ---- G = (sA)^T (sA) via MFMA: A-frag row = lane&15, k = (lane>>4)*8 + j
  const int fc = lane & 15, fq = lane >> 4;
  short8 fa, fb;
  {
    const float* rp = &At[fc * 68 + fq * 8];
    const float4 a0 = *(const float4*)(rp + 0);
    const float4 a1 = *(const float4*)(rp + 4);
    const float4 b0 = *(const float4*)(rp + 32);
    const float4 b1 = *(const float4*)(rp + 36);
    union { __hip_bfloat16 h[8]; short8 s8; } pa, pb;
    pa.h[0]=__float2bfloat16(a0.x); pa.h[1]=__float2bfloat16(a0.y);
    pa.h[2]=__float2bfloat16(a0.z); pa.h[3]=__float2bfloat16(a0.w);
    pa.h[4]=__float2bfloat16(a1.x); pa.h[5]=__float2bfloat16(a1.y);
    pa.h[6]=__float2bfloat16(a1.z); pa.h[7]=__float2bfloat16(a1.w);
    pb.h[0]=__float2bfloat16(b0.x); pb.h[1]=__float2bfloat16(b0.y);
    pb.h[2]=__float2bfloat16(b0.z); pb.h[3]=__float2bfloat16(b0.w);
    pb.h[4]=__float2bfloat16(b1.x); pb.h[5]=__float2bfloat16(b1.y);
    pb.h[6]=__float2bfloat16(b1.z); pb.h[7]=__float2bfloat16(b1.w);
    fa = pa.s8; fb = pb.s8;
  }
  floatx4 gacc = {};
  gacc = __builtin_amdgcn_mfma_f32_16x16x32_bf16(fa, fa, gacc, 0, 0, 0);
  gacc = __builtin_amdgcn_mfma_f32_16x16x32_bf16(fb, fb, gacc, 0, 0, 0);
  // gacc[j] = G[fq*4+j][fc]

  // Frobenius norm of G (each entry exactly once across the frag)
  float ss = gacc[0]*gacc[0] + gacc[1]*gacc[1] + gacc[2]*gacc[2] + gacc[3]*gacc[3];
#pragma unroll
  for (int o = 32; o > 0; o >>= 1) ss += __shfl_xor(ss, o, 64);
  const float gf = rsqrtf(ss + 1e-30f);        // 1/||G||_F

  // Y0 = G/||G||_F (scatter by frag layout), Z0 = I (target layout)
#pragma unroll
  for (int j = 0; j < 4; ++j) Yb[(fq * 4 + j) * MS + fc] = gacc[j] * gf;
  const int r  = lane >> 2;          // my output row  (0..15)
  const int c0 = (lane & 3) * 4;     // my 4-col block
  *(float4*)&Zb[r * MS + c0] = make_float4(r == c0+0 ? 1.f : 0.f,
                                           r == c0+1 ? 1.f : 0.f,
                                           r == c0+2 ? 1.f : 0.f,
                                           r == c0+3 ? 1.f : 0.f);
  __syncthreads();

  for (int it = 0; it < iters; ++it) {
    // load my Z row and Y row (contiguous, b128) -- Z is not written in phase 1,
    // so zr stays valid for phase 2.
    float zr[16], yr[16];
    {
      const float4 za = *(const float4*)&Zb[r * MS + 0];
      const float4 zb4 = *(const float4*)&Zb[r * MS + 4];
      const float4 zc = *(const float4*)&Zb[r * MS + 8];
      const float4 zd = *(const float4*)&Zb[r * MS + 12];
      zr[0]=za.x; zr[1]=za.y; zr[2]=za.z; zr[3]=za.w;
      zr[4]=zb4.x; zr[5]=zb4.y; zr[6]=zb4.z; zr[7]=zb4.w;
      zr[8]=zc.x; zr[9]=zc.y; zr[10]=zc.z; zr[11]=zc.w;
      zr[12]=zd.x; zr[13]=zd.y; zr[14]=zd.z; zr[15]=zd.w;
      const float4 ya = *(const float4*)&Yb[r * MS + 0];
      const float4 yb4 = *(const float4*)&Yb[r * MS + 4];
      const float4 yc = *(const float4*)&Yb[r * MS + 8];
      const float4 yd = *(const float4*)&Yb[r * MS + 12];
      yr[0]=ya.x; yr[1]=ya.y; yr[2]=ya.z; yr[3]=ya.w;
      yr[4]=yb4.x; yr[5]=yb4.y; yr[6]=yb4.z; yr[7]=yb4.w;
      yr[8]=yc.x; yr[9]=yc.y; yr[10]=yc.z; yr[11]=yc.w;
      yr[12]=yd.x; yr[13]=yd.y; yr[14]=yd.z; yr[15]=yd.w;
    }
    // T = 0.5*(3I - Z*Y)
    float p0=0.f, p1=0.f, p2=0.f, p3=0.f;
#pragma unroll
    for (int k = 0; k < 16; ++k) {
      const float4 y4 = *(const float4*)&Yb[k * MS + c0];
      p0 = fmaf(zr[k], y4.x, p0); p1 = fmaf(zr[k], y4.y, p1);
      p2 = fmaf(zr[k], y4.z, p2); p3 = fmaf(zr[k], y4.w, p3);
    }
    float4 tv;
    tv.x = 0.5f * ((r == c0+0 ? 3.f : 0.f) - p0);
    tv.y = 0.5f * ((r == c0+1 ? 3.f : 0.f) - p1);
    tv.z = 0.5f * ((r == c0+2 ? 3.f : 0.f) - p2);
    tv.w = 0.5f * ((r == c0+3 ? 3.f : 0.f) - p3);
    *(float4*)&Tb[r * MS + c0] = tv;
    __syncthreads();                         // T visible
    // Ynew = Y*T ; Znew = Z*T  (all iterates symmetric & commuting)
    float4 py = make_float4(0,0,0,0), pz = make_float4(0,0,0,0);
#pragma unroll
    for (int k = 0; k < 16; ++k) {
      const float4 t4 = *(const float4*)&Tb[k * MS + c0];
      py.x = fmaf(yr[k], t4.x, py.x); py.y = fmaf(yr[k], t4.y, py.y);
      py.z = fmaf(yr[k], t4.z, py.z); py.w = fmaf(yr[k], t4.w, py.w);
      pz.x = fmaf(zr[k], t4.x, pz.x); pz.y = fmaf(zr[k], t4.y, pz.y);
      pz.z = fmaf(zr[k], t4.z, pz.z); pz.w = fmaf(zr[k], t4.w, pz.w);
    }
    // in-place update: safe within a single wave (all reads precede writes
    // in the one lockstep instruction stream; LDS ops in-order per wave)
    *(float4*)&Yb[r * MS + c0] = py;
    *(float4*)&Zb[r * MS + c0] = pz;
    __syncthreads();                         // Y,Z visible for next iter
  }

  // Z converged to (G/||G||_F)^{-1/2} = ||G||_F^{1/2} G^{-1/2}
  // => U = v * Z * sqrt(gf)  (gf = 1/||G||_F); fold sqrt(gf) into v.
  const float us = sqrtf(gf);
#pragma unroll
  for (int j = 0; j < 16; ++j) v[j] *= us;

  // Up[i][j] = sum_k v[i][k] * Z[k][j]   (lane = row i)
  float up[16] = {};
#pragma unroll
  for (int k = 0; k < 16; ++k) {
    const float a = v[k];
#pragma unroll
    for (int j0 = 0; j0 < 16; j0 += 4) {
      const float4 z4 = *(const float4*)&Zb[k * MS + j0];  // uniform -> broadcast
      up[j0+0] = fmaf(a, z4.x, up[j0+0]);
      up[j0+1] = fmaf(a, z4.y, up[j0+1]);
      up[j0+2] = fmaf(a, z4.z, up[j0+2]);
      up[j0+3] = fmaf(a, z4.w, up[j0+3]);
    }
  }
  float* dst = Xg + (size_t)row * DD + lane * 16;
#pragma unroll
  for (int q = 0; q < 4; ++q)
    *(float4*)(dst + q*4) = make_float4(up[q*4], up[q*4+1], up[q*4+2], up[q*4+3]);
  union { __hip_bfloat16 hh[16]; uint4 u[2]; } pk;
#pragma unroll
  for (int j = 0; j < 16; ++j) pk.hh[j] = __float2bfloat16(up[j]);
  uint4* sd = (uint4*)(stage + ((size_t)layer * NROWS + row) * DD + lane * 16);
  sd[0] = pk.u[0]; sd[1] = pk.u[1];
}

// ---------------------------------------------------------------- transpose epilogue
// stage (l, row, d) bf16 -> out (row, d, l) fp32, coalesced both ways via LDS
__global__ __launch_bounds__(256) void transpose_kernel(
    const __hip_bfloat16* __restrict__ stage, float* __restrict__ outT)
{
  __shared__ float buf[256 * 18];
  const int row = blockIdx.y;          // 0..3071
  const int d0  = blockIdx.x * 256;    // 0,256,512,768
  const int t   = threadIdx.x;
  for (int l = 0; l < NLAY; ++l)
    buf[t * 18 + l] = __bfloat162float(stage[((size_t)l * NROWS + row) * DD + d0 + t]);
  __syncthreads();
  const size_t ob = (size_t)(row * DD + d0) * NLAY;
  for (int i = 0; i < NLAY; ++i) {
    const int idx = i * 256 + t;       // < 4352
    const int dd = idx / 17, ll = idx % 17;
    outT[ob + idx] = buf[dd * 18 + ll];
  }
}

// ---------------------------------------------------------------- classify
// Z = U @ S[:16,:16] @ V^T (64x64); logits = Z @ Wc^T + bc; softmax
__global__ __launch_bounds__(256) void classify_kernel(
    const float* __restrict__ X, const float* __restrict__ Wc,
    const float* __restrict__ bc, float* __restrict__ out)
{
  __shared__ float U[64*17], S[16*17], V[64*17], T[64*17];
  __shared__ float Z[4096];
  __shared__ float wsum[4][10];
  const int b = blockIdx.x, t = threadIdx.x;
  const float* x0 = X + (size_t)(b*3+0) * DD;
  const float* x1 = X + (size_t)(b*3+1) * DD;
  const float* x2 = X + (size_t)(b*3+2) * DD;
  for (int e = t; e < 1024; e += 256) {
    const int i = e >> 4, j = e & 15;
    U[i*17+j] = x0[e];
    V[i*17+j] = x2[e];
  }
  { const int i = t >> 4, j = t & 15; if (t < 256) S[i*17+j] = x1[i*16+j]; }
  __syncthreads();
  for (int e = t; e < 1024; e += 256) {     // T = U @ S
    const int i = e >> 4, j = e & 15;
    float a = 0.f;
    for (int k = 0; k < 16; ++k) a = fmaf(U[i*17+k], S[k*17+j], a);
    T[i*17+j] = a;
  }
  __syncthreads();
  for (int e = t; e < 4096; e += 256) {     // Z = T @ V^T
    const int i = e >> 6, j = e & 63;
    float a = 0.f;
    for (int k = 0; k < 16; ++k) a = fmaf(T[i*17+k], V[j*17+k], a);
    Z[e] = a;
  }
  __syncthreads();
  // logits: read Z once, 10 register accumulators, wave shuffle reduce, 1 barrier
  float part[10] = {};
  for (int e = t; e < 4096; e += 256) {
    const float z = Z[e];
#pragma unroll
    for (int n = 0; n < 10; ++n) part[n] = fmaf(z, Wc[(size_t)n * 4096 + e], part[n]);
  }
#pragma unroll
  for (int n = 0; n < 10; ++n) {
#pragma unroll
    for (int off = 32; off > 0; off >>= 1) part[n] += __shfl_xor(part[n], off, 64);
  }
  if ((t & 63) == 0) {
#pragma unroll
    for (int n = 0; n < 10; ++n) wsum[t >> 6][n] = part[n];
  }
  __syncthreads();
  if (t == 0) {
    float logits[10];
#pragma unroll
    for (int n = 0; n < 10; ++n)
      logits[n] = wsum[0][n] + wsum[1][n] + wsum[2][n] + wsum[3][n] + bc[n];
    float mx = logits[0];
    for (int n = 1; n < 10; ++n) mx = fmaxf(mx, logits[n]);
    float ex[10], sm = 0.f;
    for (int n = 0; n < 10; ++n) { ex[n] = expf(logits[n] - mx); sm += ex[n]; }
    const float inv = 1.f / sm;
    for (int n = 0; n < 10; ++n) {
      out[b*10 + n] = ex[n] * inv;          // X_predicted
      out[10240 + b*10 + n] = logits[n];    // X_classified
    }
  }
}

// ---------------------------------------------------------------- launch
extern "C" void kernel_launch(void* const* d_in, const int* in_sizes, int n_in,
                              void* d_out, int out_size, void* d_ws, size_t ws_size,
                              hipStream_t stream) {
  const float* Xin = (const float*)d_in[0];
  const float* hp  = (const float*)d_in[1];
  const float* W0  = (const float*)d_in[2];
  const float* Ws  = (const float*)d_in[3];
  const float* bs  = (const float*)d_in[4];
  const float* Wc  = (const float*)d_in[5];
  const float* bc  = (const float*)d_in[6];
  float* out = (float*)d_out;

  char* ws = (char*)d_ws;
  float* Xb = (float*)ws;                                   // 3072*1024 f32
  float* Yb = Xb + (size_t)NROWS * DD;                      // 3072*1024 f32
  __hip_bfloat16* stage =
      (__hip_bfloat16*)(ws + 2 * (size_t)NROWS * DD * 4);   // 17*3072*1024 bf16
  ushort* X0bf = (ushort*)(ws + 2 * (size_t)NROWS * DD * 4
                              + (size_t)NLAY * NROWS * DD * 2);   // 3072*1024 bf16
  ushort* Wbf  = X0bf + (size_t)NROWS * DD;                 // 17*1024*1024 bf16

  convw_kernel<<<17408, 256, 0, stream>>>(W0, Ws, Wbf);
  prep_kernel<<<NROWS, 256, 0, stream>>>(Xin, X0bf);

  // layer 0: Linear (no bias), then projection
  gemm_kernel<<<384, 256, 0, stream>>>(X0bf, Wbf, Xb, bs, hp, Yb, 0);
  proj_kernel<<<3072, 64, 0, stream>>>(Yb, Xb, stage, 0, 13);

  for (int l = 0; l < 16; ++l) {
    gemm_kernel<<<384, 256, 0, stream>>>(
        (const ushort*)(stage + (size_t)l * NROWS * DD),
        Wbf + (size_t)(l + 1) * DD * DD,
        Xb, bs + (size_t)l * DD, hp, Yb, 1);
    proj_kernel<<<3072, 64, 0, stream>>>(Yb, Xb, stage, l + 1, 9);
  }

  transpose_kernel<<<dim3(4, NROWS), 256, 0, stream>>>(stage, out + 20480);
  classify_kernel<<<1024, 256, 0, stream>>>(Xb, Wc, bc, out);
}

// Round 3
// 1004.316 us; speedup vs baseline: 1.4636x; 1.0644x over previous
//
#include <hip/hip_runtime.h>
#include <hip/hip_bf16.h>

#define DD    1024
#define NROWS 3072
#define NLAY  17
#define MS    20

typedef __attribute__((ext_vector_type(8))) short short8;
typedef __attribute__((ext_vector_type(4))) float floatx4;

// ---------------------------------------------------------------- weight convert
__global__ __launch_bounds__(256) void convw_kernel(const float* __restrict__ W0,
                                                    const float* __restrict__ Ws,
                                                    ushort* __restrict__ Wbf) {
  const size_t i4 = ((size_t)blockIdx.x * 256 + threadIdx.x) * 4;
  float4 v;
  if (i4 < 1048576) v = *(const float4*)(W0 + i4);
  else              v = *(const float4*)(Ws + (i4 - 1048576));
  union { __hip_bfloat16 h[4]; ushort u[4]; } pk;
  pk.h[0] = __float2bfloat16(v.x); pk.h[1] = __float2bfloat16(v.y);
  pk.h[2] = __float2bfloat16(v.z); pk.h[3] = __float2bfloat16(v.w);
  *(ushort4*)(Wbf + i4) = *(ushort4*)pk.u;
}

// ---------------------------------------------------------------- prep
__global__ __launch_bounds__(256) void prep_kernel(const float* __restrict__ Xin,
                                                   ushort* __restrict__ X0bf) {
  const int row = blockIdx.x;           // 0..3071  (= b*3 + c)
  const int c   = row % 3;
  const float* src = Xin + (size_t)row * DD;
  ushort* dst = X0bf + (size_t)row * DD;
  for (int t = threadIdx.x; t < DD; t += 256) {
    float v;
    if (c == 2) v = src[(t & 15) * 64 + (t >> 4)];
    else        v = src[t];
    __hip_bfloat16 h = __float2bfloat16(v);
    dst[t] = *(ushort*)&h;
  }
}

// ---------------------------------------------------------------- MFMA GEMM
// 128x64 tile (M x N), BK=32, 4 waves 2x2, grid 384, XCD-chunked swizzle.
__global__ __launch_bounds__(256) void gemm_kernel(
    const ushort* __restrict__ Abf, const ushort* __restrict__ Wbf,
    const float* __restrict__ Xres, const float* __restrict__ bias,
    const float* __restrict__ hp, float* __restrict__ Y, int fuse)
{
  __shared__ __align__(16) ushort As[128 * 32];
  __shared__ __align__(16) ushort Bs[64 * 32];
  const int tid  = threadIdx.x;
  const int wave = tid >> 6, lane = tid & 63;

  const int id = blockIdx.x;
  const int w  = (id & 7) * 48 + (id >> 3);
  const int bm = (w >> 4) * 128;
  const int bn = (w & 15) * 64;

  const int srow = wave * 16 + (lane >> 2);
  const int scol = (lane & 3) * 8;
  const ushort* ga0 = Abf + (size_t)(bm + srow) * DD + scol;
  const ushort* gb0 = Wbf + (size_t)(bn + srow) * DD + scol;

  const int wm0 = (wave >> 1) * 64, wn0 = (wave & 1) * 32;
  const int m = lane & 15, quad = lane >> 4;

  floatx4 acc[4][2] = {};

  for (int k0 = 0; k0 < DD; k0 += 32) {
    __syncthreads();
#pragma unroll
    for (int q = 0; q < 2; ++q) {
      __builtin_amdgcn_global_load_lds(
          (const __attribute__((address_space(1))) unsigned int*)(ga0 + (size_t)q * 64 * DD + k0),
          (__attribute__((address_space(3))) unsigned int*)&As[(q * 64 + wave * 16) * 32],
          16, 0, 0);
    }
    __builtin_amdgcn_global_load_lds(
        (const __attribute__((address_space(1))) unsigned int*)(gb0 + k0),
        (__attribute__((address_space(3))) unsigned int*)&Bs[(wave * 16) * 32],
        16, 0, 0);
    __syncthreads();

    short8 av[4], bv[2];
#pragma unroll
    for (int i = 0; i < 4; ++i)
      av[i] = *(const short8*)&As[(wm0 + i * 16 + m) * 32 + quad * 8];
#pragma unroll
    for (int j = 0; j < 2; ++j)
      bv[j] = *(const short8*)&Bs[(wn0 + j * 16 + m) * 32 + quad * 8];
#pragma unroll
    for (int i = 0; i < 4; ++i)
#pragma unroll
      for (int j = 0; j < 2; ++j)
        acc[i][j] = __builtin_amdgcn_mfma_f32_16x16x32_bf16(av[i], bv[j], acc[i][j], 0, 0, 0);
  }

  const float h = fuse ? hp[0] : 0.0f;
#pragma unroll
  for (int i = 0; i < 4; ++i) {
#pragma unroll
    for (int r = 0; r < 4; ++r) {
      const int grow = bm + wm0 + i * 16 + quad * 4 + r;
      float* yr = Y + (size_t)grow * DD;
      const float* xr = Xres + (size_t)grow * DD;
#pragma unroll
      for (int j = 0; j < 2; ++j) {
        const int gcol = bn + wn0 + j * 16 + m;
        float d = acc[i][j][r];
        if (fuse) d = xr[gcol] + h * fmaxf(d + bias[gcol], 0.0f);
        yr[gcol] = d;
      }
    }
  }
}

// ---------------------------------------------------------------- projection
// One wave per block. Newton-Schulz entirely in MFMA fragments.
//
// Key identity: for SYMMETRIC 16x16 M, the mfma_f32_16x16x32_bf16 D-fragment
// (lane holds D[4q+j][c], c=lane&15, q=lane>>4) written to LDS row c at cols
// 4q..4q+3 (one b64) yields M[r][k] row-major; the A/B-fragment is then ONE
// b128 read (row lane&15, k=8*(lane>>4)+d), with k>=16 hitting a pre-zeroed
// pad (16x16 operand inside K=32). fp32 accuracy via hi/lo bf16 split:
// M ~ Mh+Ml, product = MhNh + MhNl + MlNh (3 MFMAs, err ~6e-5/entry).
// Per NS iter: 12 LDS insts + 9 MFMA + ~80 VALU, no barriers (wave-local).
// asm memory clobbers fence TBAA across mixed-type LDS pointer casts;
// same-wave ds ordering is in-order on the LDS pipe.
__device__ __forceinline__ void split_wr(ushort* Bh, ushort* Bl, int c, int q, floatx4 a) {
  union { ushort u[4]; uint2 d; } ph, pl;
#pragma unroll
  for (int j = 0; j < 4; ++j) {
    const float x = a[j];
    __hip_bfloat16 hb = __float2bfloat16(x);
    const float hf = __bfloat162float(hb);
    __hip_bfloat16 lb = __float2bfloat16(x - hf);
    ph.u[j] = *(const ushort*)&hb;
    pl.u[j] = *(const ushort*)&lb;
  }
  *(uint2*)&Bh[c * 40 + q * 4] = ph.d;
  *(uint2*)&Bl[c * 40 + q * 4] = pl.d;
}

__global__ __launch_bounds__(64) void proj_kernel(
    const float* __restrict__ Yg, float* __restrict__ Xg,
    __hip_bfloat16* __restrict__ stage, int layer, int iters)
{
  // unioned pool: prologue {ATl 1152 + Bh 640 + Bl 640}, loop {Bh,Bl},
  // epilogue {Ah 2560 + Al 2560, Ub(f32 64x20) overlapping}
  __shared__ __align__(16) ushort POOL[5632];   // 11264 B

  const int lane = threadIdx.x;                  // 0..63

  if (blockIdx.x >= 2048) {                      // ---- channel-1 copy path
    const int b = blockIdx.x - 2048;
    const int row = b * 3 + 1;
    const float* src = Yg + (size_t)row * DD + lane * 16;
    float* dst = Xg + (size_t)row * DD + lane * 16;
    float v[16];
#pragma unroll
    for (int q = 0; q < 4; ++q) {
      const float4 t4 = *(const float4*)(src + q * 4);
      v[q*4+0]=t4.x; v[q*4+1]=t4.y; v[q*4+2]=t4.z; v[q*4+3]=t4.w;
      *(float4*)(dst + q * 4) = t4;
    }
    union { __hip_bfloat16 hh[16]; uint4 u[2]; } pk;
#pragma unroll
    for (int j = 0; j < 16; ++j) pk.hh[j] = __float2bfloat16(v[j]);
    uint4* sd = (uint4*)(stage + ((size_t)layer * NROWS + row) * DD + lane * 16);
    sd[0] = pk.u[0]; sd[1] = pk.u[1];
    return;
  }

  const int p = blockIdx.x;              // 0..2047
  const int b = p >> 1;
  const int row = b * 3 + (p & 1) * 2;   // channel 0 or 2
  const float* src = Yg + (size_t)row * DD + lane * 16;

  // lane = row i of A(64x16); v = A[i][0..15]
  float v[16];
#pragma unroll
  for (int q = 0; q < 4; ++q) {
    const float4 t4 = *(const float4*)(src + q * 4);
    v[q*4+0]=t4.x; v[q*4+1]=t4.y; v[q*4+2]=t4.z; v[q*4+3]=t4.w;
  }
  float nrm = 0.f;
#pragma unroll
  for (int j = 0; j < 16; ++j) nrm += v[j] * v[j];
#pragma unroll
  for (int o = 32; o > 0; o >>= 1) nrm += __shfl_xor(nrm, o, 64);
  const float s = rsqrtf(nrm + 1e-30f);
#pragma unroll
  for (int j = 0; j < 16; ++j) v[j] *= s;       // v = scaled A row

  ushort* ATl = POOL;                 // A^T bf16 [16][72] (144B stride)
  ushort* Bh  = POOL + 1152;          // relayout buf hi [16][40] (80B stride)
  ushort* Bl  = POOL + 1792;          // relayout buf lo
  const int fr = lane & 15, fq = lane >> 4;

  // write A^T (bf16), zero-pad Bh/Bl cols 16..31 (once)
#pragma unroll
  for (int j = 0; j < 16; ++j) {
    __hip_bfloat16 hb = __float2bfloat16(v[j]);
    ATl[j * 72 + lane] = *(const ushort*)&hb;
  }
  *(uint2*)&Bh[fr * 40 + 16 + fq * 4] = make_uint2(0u, 0u);
  *(uint2*)&Bl[fr * 40 + 16 + fq * 4] = make_uint2(0u, 0u);
  asm volatile("" ::: "memory");

  // ---- G = (sA)^T (sA) via 2x MFMA (K=64); A-frag == B-frag by symmetry
  short8 g1 = *(const short8*)&ATl[fr * 72 + fq * 8];
  short8 g2 = *(const short8*)&ATl[fr * 72 + 32 + fq * 8];
  floatx4 gacc = {};
  gacc = __builtin_amdgcn_mfma_f32_16x16x32_bf16(g1, g1, gacc, 0, 0, 0);
  gacc = __builtin_amdgcn_mfma_f32_16x16x32_bf16(g2, g2, gacc, 0, 0, 0);
  // gacc[j] = G[fq*4+j][fr]

  float ss = gacc[0]*gacc[0] + gacc[1]*gacc[1] + gacc[2]*gacc[2] + gacc[3]*gacc[3];
#pragma unroll
  for (int o = 32; o > 0; o >>= 1) ss += __shfl_xor(ss, o, 64);
  const float gf = rsqrtf(ss + 1e-30f);        // 1/||G||_F

  // Y0 = G/||G||_F -> frags; Z0 = I frag (exact, register-only)
  floatx4 yd;
#pragma unroll
  for (int j = 0; j < 4; ++j) yd[j] = gacc[j] * gf;
  split_wr(Bh, Bl, fr, fq, yd);
  asm volatile("" ::: "memory");
  short8 Yh = *(const short8*)&Bh[fr * 40 + fq * 8];
  short8 Yl = *(const short8*)&Bl[fr * 40 + fq * 8];
  short8 Zh, Zl;
#pragma unroll
  for (int d = 0; d < 8; ++d) {
    Zh[d] = (fr == fq * 8 + d) ? (short)0x3F80 : (short)0;
    Zl[d] = 0;
  }

  for (int it = 0; it < iters; ++it) {
    // W = Z*Y
    floatx4 wv = {};
    wv = __builtin_amdgcn_mfma_f32_16x16x32_bf16(Zh, Yh, wv, 0, 0, 0);
    wv = __builtin_amdgcn_mfma_f32_16x16x32_bf16(Zh, Yl, wv, 0, 0, 0);
    wv = __builtin_amdgcn_mfma_f32_16x16x32_bf16(Zl, Yh, wv, 0, 0, 0);
    // T = 1.5I - 0.5W
    floatx4 td;
#pragma unroll
    for (int j = 0; j < 4; ++j)
      td[j] = ((fq * 4 + j == fr) ? 1.5f : 0.f) - 0.5f * wv[j];
    split_wr(Bh, Bl, fr, fq, td);
    asm volatile("" ::: "memory");
    short8 Th = *(const short8*)&Bh[fr * 40 + fq * 8];
    short8 Tl = *(const short8*)&Bl[fr * 40 + fq * 8];
    // Z' = Z*T (always); Y' = Y*T (skip on last iter)
    floatx4 zd = {};
    zd = __builtin_amdgcn_mfma_f32_16x16x32_bf16(Zh, Th, zd, 0, 0, 0);
    zd = __builtin_amdgcn_mfma_f32_16x16x32_bf16(Zh, Tl, zd, 0, 0, 0);
    zd = __builtin_amdgcn_mfma_f32_16x16x32_bf16(Zl, Th, zd, 0, 0, 0);
    if (it < iters - 1) {
      floatx4 yn = {};
      yn = __builtin_amdgcn_mfma_f32_16x16x32_bf16(Yh, Th, yn, 0, 0, 0);
      yn = __builtin_amdgcn_mfma_f32_16x16x32_bf16(Yh, Tl, yn, 0, 0, 0);
      yn = __builtin_amdgcn_mfma_f32_16x16x32_bf16(Yl, Th, yn, 0, 0, 0);
      split_wr(Bh, Bl, fr, fq, yn);
      asm volatile("" ::: "memory");
      Yh = *(const short8*)&Bh[fr * 40 + fq * 8];
      Yl = *(const short8*)&Bl[fr * 40 + fq * 8];
    }
    split_wr(Bh, Bl, fr, fq, zd);
    asm volatile("" ::: "memory");
    Zh = *(const short8*)&Bh[fr * 40 + fq * 8];
    Zl = *(const short8*)&Bl[fr * 40 + fq * 8];
  }

  // ---- U = (v*sqrt(gf)) * Z via 4 chunks x 3 MFMA; Z-frag already in regs.
  const float us = sqrtf(gf);
  asm volatile("" ::: "memory");
  ushort* Ah = POOL;           // [64][40] bf16 hi (80B stride), cols 16..31 zero
  ushort* Al = POOL + 2560;    // lo
  {
    union { ushort u[16]; uint4 q4[2]; } rh, rl;
#pragma unroll
    for (int j = 0; j < 16; ++j) {
      const float x = v[j] * us;
      __hip_bfloat16 hb = __float2bfloat16(x);
      const float hf = __bfloat162float(hb);
      __hip_bfloat16 lb = __float2bfloat16(x - hf);
      rh.u[j] = *(const ushort*)&hb;
      rl.u[j] = *(const ushort*)&lb;
    }
    *(uint4*)&Ah[lane * 40]      = rh.q4[0];
    *(uint4*)&Ah[lane * 40 + 8]  = rh.q4[1];
    *(uint4*)&Al[lane * 40]      = rl.q4[0];
    *(uint4*)&Al[lane * 40 + 8]  = rl.q4[1];
    const uint4 zz = make_uint4(0u, 0u, 0u, 0u);
    *(uint4*)&Ah[lane * 40 + 16] = zz; *(uint4*)&Ah[lane * 40 + 24] = zz;
    *(uint4*)&Al[lane * 40 + 16] = zz; *(uint4*)&Al[lane * 40 + 24] = zz;
  }
  asm volatile("" ::: "memory");
  short8 ah[4], al[4];
#pragma unroll
  for (int m4 = 0; m4 < 4; ++m4) {
    ah[m4] = *(const short8*)&Ah[(m4 * 16 + fr) * 40 + fq * 8];
    al[m4] = *(const short8*)&Al[(m4 * 16 + fr) * 40 + fq * 8];
  }
  floatx4 um[4];
#pragma unroll
  for (int m4 = 0; m4 < 4; ++m4) {
    floatx4 a = {};
    a = __builtin_amdgcn_mfma_f32_16x16x32_bf16(ah[m4], Zh, a, 0, 0, 0);
    a = __builtin_amdgcn_mfma_f32_16x16x32_bf16(ah[m4], Zl, a, 0, 0, 0);
    a = __builtin_amdgcn_mfma_f32_16x16x32_bf16(al[m4], Zh, a, 0, 0, 0);
    um[m4] = a;
  }
  asm volatile("" ::: "memory");
  float* Ub = (float*)POOL;            // [64][20] f32 (80B stride)
#pragma unroll
  for (int m4 = 0; m4 < 4; ++m4)
#pragma unroll
    for (int j = 0; j < 4; ++j)
      Ub[(m4 * 16 + fq * 4 + j) * 20 + fr] = um[m4][j];
  asm volatile("" ::: "memory");
  float up[16];
#pragma unroll
  for (int i = 0; i < 4; ++i) {
    const float4 t4 = *(const float4*)&Ub[lane * 20 + i * 4];
    up[i*4+0]=t4.x; up[i*4+1]=t4.y; up[i*4+2]=t4.z; up[i*4+3]=t4.w;
  }
  float* dst = Xg + (size_t)row * DD + lane * 16;
#pragma unroll
  for (int q = 0; q < 4; ++q)
    *(float4*)(dst + q*4) = make_float4(up[q*4], up[q*4+1], up[q*4+2], up[q*4+3]);
  union { __hip_bfloat16 hh[16]; uint4 u[2]; } pk;
#pragma unroll
  for (int j = 0; j < 16; ++j) pk.hh[j] = __float2bfloat16(up[j]);
  uint4* sd = (uint4*)(stage + ((size_t)layer * NROWS + row) * DD + lane * 16);
  sd[0] = pk.u[0]; sd[1] = pk.u[1];
}

// ---------------------------------------------------------------- transpose epilogue
__global__ __launch_bounds__(256) void transpose_kernel(
    const __hip_bfloat16* __restrict__ stage, float* __restrict__ outT)
{
  __shared__ float buf[256 * 18];
  const int row = blockIdx.y;
  const int d0  = blockIdx.x * 256;
  const int t   = threadIdx.x;
  for (int l = 0; l < NLAY; ++l)
    buf[t * 18 + l] = __bfloat162float(stage[((size_t)l * NROWS + row) * DD + d0 + t]);
  __syncthreads();
  const size_t ob = (size_t)(row * DD + d0) * NLAY;
  for (int i = 0; i < NLAY; ++i) {
    const int idx = i * 256 + t;
    const int dd = idx / 17, ll = idx % 17;
    outT[ob + idx] = buf[dd * 18 + ll];
  }
}

// ---------------------------------------------------------------- classify
__global__ __launch_bounds__(256) void classify_kernel(
    const float* __restrict__ X, const float* __restrict__ Wc,
    const float* __restrict__ bc, float* __restrict__ out)
{
  __shared__ float U[64*17], S[16*17], V[64*17], T[64*17];
  __shared__ float Z[4096];
  __shared__ float wsum[4][10];
  const int b = blockIdx.x, t = threadIdx.x;
  const float* x0 = X + (size_t)(b*3+0) * DD;
  const float* x1 = X + (size_t)(b*3+1) * DD;
  const float* x2 = X + (size_t)(b*3+2) * DD;
  for (int e = t; e < 1024; e += 256) {
    const int i = e >> 4, j = e & 15;
    U[i*17+j] = x0[e];
    V[i*17+j] = x2[e];
  }
  { const int i = t >> 4, j = t & 15; if (t < 256) S[i*17+j] = x1[i*16+j]; }
  __syncthreads();
  for (int e = t; e < 1024; e += 256) {     // T = U @ S
    const int i = e >> 4, j = e & 15;
    float a = 0.f;
    for (int k = 0; k < 16; ++k) a = fmaf(U[i*17+k], S[k*17+j], a);
    T[i*17+j] = a;
  }
  __syncthreads();
  for (int e = t; e < 4096; e += 256) {     // Z = T @ V^T
    const int i = e >> 6, j = e & 63;
    float a = 0.f;
    for (int k = 0; k < 16; ++k) a = fmaf(T[i*17+k], V[j*17+k], a);
    Z[e] = a;
  }
  __syncthreads();
  float part[10] = {};
  for (int e = t; e < 4096; e += 256) {
    const float z = Z[e];
#pragma unroll
    for (int n = 0; n < 10; ++n) part[n] = fmaf(z, Wc[(size_t)n * 4096 + e], part[n]);
  }
#pragma unroll
  for (int n = 0; n < 10; ++n) {
#pragma unroll
    for (int off = 32; off > 0; off >>= 1) part[n] += __shfl_xor(part[n], off, 64);
  }
  if ((t & 63) == 0) {
#pragma unroll
    for (int n = 0; n < 10; ++n) wsum[t >> 6][n] = part[n];
  }
  __syncthreads();
  if (t == 0) {
    float logits[10];
#pragma unroll
    for (int n = 0; n < 10; ++n)
      logits[n] = wsum[0][n] + wsum[1][n] + wsum[2][n] + wsum[3][n] + bc[n];
    float mx = logits[0];
    for (int n = 1; n < 10; ++n) mx = fmaxf(mx, logits[n]);
    float ex[10], sm = 0.f;
    for (int n = 0; n < 10; ++n) { ex[n] = expf(logits[n] - mx); sm += ex[n]; }
    const float inv = 1.f / sm;
    for (int n = 0; n < 10; ++n) {
      out[b*10 + n] = ex[n] * inv;
      out[10240 + b*10 + n] = logits[n];
    }
  }
}

// ---------------------------------------------------------------- launch
extern "C" void kernel_launch(void* const* d_in, const int* in_sizes, int n_in,
                              void* d_out, int out_size, void* d_ws, size_t ws_size,
                              hipStream_t stream) {
  const float* Xin = (const float*)d_in[0];
  const float* hp  = (const float*)d_in[1];
  const float* W0  = (const float*)d_in[2];
  const float* Ws  = (const float*)d_in[3];
  const float* bs  = (const float*)d_in[4];
  const float* Wc  = (const float*)d_in[5];
  const float* bc  = (const float*)d_in[6];
  float* out = (float*)d_out;

  char* ws = (char*)d_ws;
  float* Xb = (float*)ws;
  float* Yb = Xb + (size_t)NROWS * DD;
  __hip_bfloat16* stage =
      (__hip_bfloat16*)(ws + 2 * (size_t)NROWS * DD * 4);
  ushort* X0bf = (ushort*)(ws + 2 * (size_t)NROWS * DD * 4
                              + (size_t)NLAY * NROWS * DD * 2);
  ushort* Wbf  = X0bf + (size_t)NROWS * DD;

  convw_kernel<<<17408, 256, 0, stream>>>(W0, Ws, Wbf);
  prep_kernel<<<NROWS, 256, 0, stream>>>(Xin, X0bf);

  gemm_kernel<<<384, 256, 0, stream>>>(X0bf, Wbf, Xb, bs, hp, Yb, 0);
  proj_kernel<<<3072, 64, 0, stream>>>(Yb, Xb, stage, 0, 13);

  for (int l = 0; l < 16; ++l) {
    gemm_kernel<<<384, 256, 0, stream>>>(
        (const ushort*)(stage + (size_t)l * NROWS * DD),
        Wbf + (size_t)(l + 1) * DD * DD,
        Xb, bs + (size_t)l * DD, hp, Yb, 1);
    proj_kernel<<<3072, 64, 0, stream>>>(Yb, Xb, stage, l + 1, 9);
  }

  transpose_kernel<<<dim3(4, NROWS), 256, 0, stream>>>(stage, out + 20480);
  classify_kernel<<<1024, 256, 0, stream>>>(Xb, Wc, bc, out);
}

// Round 4
// 975.541 us; speedup vs baseline: 1.5067x; 1.0295x over previous
//
#include <hip/hip_runtime.h>
#include <hip/hip_bf16.h>

#define DD    1024
#define NROWS 3072
#define NLAY  17

typedef __attribute__((ext_vector_type(8))) short short8;
typedef __attribute__((ext_vector_type(4))) float floatx4;

// ---------------------------------------------------------------- convert + prep (fused)
// blocks 0..17407: W0 (1M) ++ Ws (16M) fp32 -> bf16
// blocks 17408..20479: build X0 rows (bf16): ch0/ch1 copy, ch2 transpose (16,64)->(64,16)
__global__ __launch_bounds__(256) void convprep_kernel(
    const float* __restrict__ W0, const float* __restrict__ Ws,
    ushort* __restrict__ Wbf, const float* __restrict__ Xin,
    ushort* __restrict__ X0bf)
{
  if (blockIdx.x < 17408) {
    const size_t i4 = ((size_t)blockIdx.x * 256 + threadIdx.x) * 4;
    float4 v;
    if (i4 < 1048576) v = *(const float4*)(W0 + i4);
    else              v = *(const float4*)(Ws + (i4 - 1048576));
    union { __hip_bfloat16 h[4]; ushort u[4]; } pk;
    pk.h[0] = __float2bfloat16(v.x); pk.h[1] = __float2bfloat16(v.y);
    pk.h[2] = __float2bfloat16(v.z); pk.h[3] = __float2bfloat16(v.w);
    *(ushort4*)(Wbf + i4) = *(ushort4*)pk.u;
    return;
  }
  const int row = blockIdx.x - 17408;   // 0..3071  (= b*3 + c)
  const int c   = row % 3;
  const float* src = Xin + (size_t)row * DD;
  ushort* dst = X0bf + (size_t)row * DD;
  for (int t = threadIdx.x; t < DD; t += 256) {
    float v;
    if (c == 2) v = src[(t & 15) * 64 + (t >> 4)];
    else        v = src[t];
    __hip_bfloat16 h = __float2bfloat16(v);
    dst[t] = *(ushort*)&h;
  }
}

// ---------------------------------------------------------------- MFMA GEMM
// 64x64 tile, BK=32, 4 waves 2x2 (each 32x32), grid 768 = 3 blocks/CU:
// TLP hides the staging latency the 1.5-block/CU config exposed.
// Minimal 2-phase pipeline: stage tile t+1 into buf^1 BEFORE computing tile t;
// single barrier per K-step, vmcnt drain lands after the compute phase.
// Per-output accumulation order over K unchanged -> bit-identical results.
__global__ __launch_bounds__(256) void gemm_kernel(
    const ushort* __restrict__ Abf, const ushort* __restrict__ Wbf,
    const float* __restrict__ Xres, const float* __restrict__ bias,
    const float* __restrict__ hp, float* __restrict__ Y, int fuse)
{
  __shared__ __align__(16) ushort As[2][64 * 32];
  __shared__ __align__(16) ushort Bs[2][64 * 32];
  const int tid  = threadIdx.x;
  const int wave = tid >> 6, lane = tid & 63;

  // bijective XCD swizzle (768 % 8 == 0): 96 blocks/chunk
  const int id = blockIdx.x;
  const int w  = (id & 7) * 96 + (id >> 3);
  const int bm = (w >> 4) * 64;         // 48 M-tiles
  const int bn = (w & 15) * 64;         // 16 N-tiles

  // staging: wave w covers rows [w*16, +16); lane -> (row=lane>>2, 16B chunk=lane&3)
  const int srow = wave * 16 + (lane >> 2);
  const int scol = (lane & 3) * 8;
  const ushort* ga0 = Abf + (size_t)(bm + srow) * DD + scol;
  const ushort* gb0 = Wbf + (size_t)(bn + srow) * DD + scol;
  const int sdst = (wave * 16) * 32;    // ushort offset into As/Bs half

  const int wm0 = (wave >> 1) * 32, wn0 = (wave & 1) * 32;
  const int m = lane & 15, quad = lane >> 4;

  floatx4 acc[2][2] = {};

  // prologue: stage tile 0 into buf 0
  __builtin_amdgcn_global_load_lds(
      (const __attribute__((address_space(1))) unsigned int*)(ga0),
      (__attribute__((address_space(3))) unsigned int*)&As[0][sdst], 16, 0, 0);
  __builtin_amdgcn_global_load_lds(
      (const __attribute__((address_space(1))) unsigned int*)(gb0),
      (__attribute__((address_space(3))) unsigned int*)&Bs[0][sdst], 16, 0, 0);
  __syncthreads();                      // compiler drains vmcnt before barrier

  int cur = 0;
  for (int t = 0; t < 31; ++t) {
    const int k1 = (t + 1) * 32;
    // issue next-tile stage into buf^1 (consumed-last-iter, barrier-protected)
    __builtin_amdgcn_global_load_lds(
        (const __attribute__((address_space(1))) unsigned int*)(ga0 + k1),
        (__attribute__((address_space(3))) unsigned int*)&As[cur ^ 1][sdst], 16, 0, 0);
    __builtin_amdgcn_global_load_lds(
        (const __attribute__((address_space(1))) unsigned int*)(gb0 + k1),
        (__attribute__((address_space(3))) unsigned int*)&Bs[cur ^ 1][sdst], 16, 0, 0);
    // compute current tile
    short8 av[2], bv[2];
#pragma unroll
    for (int i = 0; i < 2; ++i)
      av[i] = *(const short8*)&As[cur][(wm0 + i * 16 + m) * 32 + quad * 8];
#pragma unroll
    for (int j = 0; j < 2; ++j)
      bv[j] = *(const short8*)&Bs[cur][(wn0 + j * 16 + m) * 32 + quad * 8];
#pragma unroll
    for (int i = 0; i < 2; ++i)
#pragma unroll
      for (int j = 0; j < 2; ++j)
        acc[i][j] = __builtin_amdgcn_mfma_f32_16x16x32_bf16(av[i], bv[j], acc[i][j], 0, 0, 0);
    __syncthreads();                    // drain staged loads; all waves done reading cur
    cur ^= 1;
  }
  {
    // epilogue tile (no prefetch)
    short8 av[2], bv[2];
#pragma unroll
    for (int i = 0; i < 2; ++i)
      av[i] = *(const short8*)&As[cur][(wm0 + i * 16 + m) * 32 + quad * 8];
#pragma unroll
    for (int j = 0; j < 2; ++j)
      bv[j] = *(const short8*)&Bs[cur][(wn0 + j * 16 + m) * 32 + quad * 8];
#pragma unroll
    for (int i = 0; i < 2; ++i)
#pragma unroll
      for (int j = 0; j < 2; ++j)
        acc[i][j] = __builtin_amdgcn_mfma_f32_16x16x32_bf16(av[i], bv[j], acc[i][j], 0, 0, 0);
  }

  // epilogue: C layout col=lane&15, row=quad*4+reg
  const float h = fuse ? hp[0] : 0.0f;
#pragma unroll
  for (int i = 0; i < 2; ++i) {
#pragma unroll
    for (int r = 0; r < 4; ++r) {
      const int grow = bm + wm0 + i * 16 + quad * 4 + r;
      float* yr = Y + (size_t)grow * DD;
      const float* xr = Xres + (size_t)grow * DD;
#pragma unroll
      for (int j = 0; j < 2; ++j) {
        const int gcol = bn + wn0 + j * 16 + m;
        float d = acc[i][j][r];
        if (fuse) d = xr[gcol] + h * fmaxf(d + bias[gcol], 0.0f);
        yr[gcol] = d;
      }
    }
  }
}

// ---------------------------------------------------------------- projection
// One wave per block. Newton-Schulz entirely in MFMA fragments (see R3 notes):
// symmetric-M D-fragment relayout via one b64 write + one b128 read; fp32
// accuracy via hi/lo bf16 split (3 MFMAs per product).
__device__ __forceinline__ void split_wr(ushort* Bh, ushort* Bl, int c, int q, floatx4 a) {
  union { ushort u[4]; uint2 d; } ph, pl;
#pragma unroll
  for (int j = 0; j < 4; ++j) {
    const float x = a[j];
    __hip_bfloat16 hb = __float2bfloat16(x);
    const float hf = __bfloat162float(hb);
    __hip_bfloat16 lb = __float2bfloat16(x - hf);
    ph.u[j] = *(const ushort*)&hb;
    pl.u[j] = *(const ushort*)&lb;
  }
  *(uint2*)&Bh[c * 40 + q * 4] = ph.d;
  *(uint2*)&Bl[c * 40 + q * 4] = pl.d;
}

__global__ __launch_bounds__(64) void proj_kernel(
    const float* __restrict__ Yg, float* __restrict__ Xg,
    __hip_bfloat16* __restrict__ stage, int layer, int iters)
{
  __shared__ __align__(16) ushort POOL[5632];   // 11264 B unioned pool

  const int lane = threadIdx.x;                  // 0..63

  if (blockIdx.x >= 2048) {                      // ---- channel-1 copy path
    const int b = blockIdx.x - 2048;
    const int row = b * 3 + 1;
    const float* src = Yg + (size_t)row * DD + lane * 16;
    float* dst = Xg + (size_t)row * DD + lane * 16;
    float v[16];
#pragma unroll
    for (int q = 0; q < 4; ++q) {
      const float4 t4 = *(const float4*)(src + q * 4);
      v[q*4+0]=t4.x; v[q*4+1]=t4.y; v[q*4+2]=t4.z; v[q*4+3]=t4.w;
      *(float4*)(dst + q * 4) = t4;
    }
    union { __hip_bfloat16 hh[16]; uint4 u[2]; } pk;
#pragma unroll
    for (int j = 0; j < 16; ++j) pk.hh[j] = __float2bfloat16(v[j]);
    uint4* sd = (uint4*)(stage + ((size_t)layer * NROWS + row) * DD + lane * 16);
    sd[0] = pk.u[0]; sd[1] = pk.u[1];
    return;
  }

  const int p = blockIdx.x;              // 0..2047
  const int b = p >> 1;
  const int row = b * 3 + (p & 1) * 2;   // channel 0 or 2
  const float* src = Yg + (size_t)row * DD + lane * 16;

  float v[16];
#pragma unroll
  for (int q = 0; q < 4; ++q) {
    const float4 t4 = *(const float4*)(src + q * 4);
    v[q*4+0]=t4.x; v[q*4+1]=t4.y; v[q*4+2]=t4.z; v[q*4+3]=t4.w;
  }
  float nrm = 0.f;
#pragma unroll
  for (int j = 0; j < 16; ++j) nrm += v[j] * v[j];
#pragma unroll
  for (int o = 32; o > 0; o >>= 1) nrm += __shfl_xor(nrm, o, 64);
  const float s = rsqrtf(nrm + 1e-30f);
#pragma unroll
  for (int j = 0; j < 16; ++j) v[j] *= s;       // v = scaled A row

  ushort* ATl = POOL;                 // A^T bf16 [16][72]
  ushort* Bh  = POOL + 1152;          // relayout hi [16][40]
  ushort* Bl  = POOL + 1792;          // relayout lo
  const int fr = lane & 15, fq = lane >> 4;

#pragma unroll
  for (int j = 0; j < 16; ++j) {
    __hip_bfloat16 hb = __float2bfloat16(v[j]);
    ATl[j * 72 + lane] = *(const ushort*)&hb;
  }
  *(uint2*)&Bh[fr * 40 + 16 + fq * 4] = make_uint2(0u, 0u);
  *(uint2*)&Bl[fr * 40 + 16 + fq * 4] = make_uint2(0u, 0u);
  asm volatile("" ::: "memory");

  // ---- G = (sA)^T (sA) via 2x MFMA (K=64)
  short8 g1 = *(const short8*)&ATl[fr * 72 + fq * 8];
  short8 g2 = *(const short8*)&ATl[fr * 72 + 32 + fq * 8];
  floatx4 gacc = {};
  gacc = __builtin_amdgcn_mfma_f32_16x16x32_bf16(g1, g1, gacc, 0, 0, 0);
  gacc = __builtin_amdgcn_mfma_f32_16x16x32_bf16(g2, g2, gacc, 0, 0, 0);

  float ss = gacc[0]*gacc[0] + gacc[1]*gacc[1] + gacc[2]*gacc[2] + gacc[3]*gacc[3];
#pragma unroll
  for (int o = 32; o > 0; o >>= 1) ss += __shfl_xor(ss, o, 64);
  const float gf = rsqrtf(ss + 1e-30f);        // 1/||G||_F

  floatx4 yd;
#pragma unroll
  for (int j = 0; j < 4; ++j) yd[j] = gacc[j] * gf;
  split_wr(Bh, Bl, fr, fq, yd);
  asm volatile("" ::: "memory");
  short8 Yh = *(const short8*)&Bh[fr * 40 + fq * 8];
  short8 Yl = *(const short8*)&Bl[fr * 40 + fq * 8];
  short8 Zh, Zl;
#pragma unroll
  for (int d = 0; d < 8; ++d) {
    Zh[d] = (fr == fq * 8 + d) ? (short)0x3F80 : (short)0;
    Zl[d] = 0;
  }

  for (int it = 0; it < iters; ++it) {
    floatx4 wv = {};
    wv = __builtin_amdgcn_mfma_f32_16x16x32_bf16(Zh, Yh, wv, 0, 0, 0);
    wv = __builtin_amdgcn_mfma_f32_16x16x32_bf16(Zh, Yl, wv, 0, 0, 0);
    wv = __builtin_amdgcn_mfma_f32_16x16x32_bf16(Zl, Yh, wv, 0, 0, 0);
    floatx4 td;
#pragma unroll
    for (int j = 0; j < 4; ++j)
      td[j] = ((fq * 4 + j == fr) ? 1.5f : 0.f) - 0.5f * wv[j];
    split_wr(Bh, Bl, fr, fq, td);
    asm volatile("" ::: "memory");
    short8 Th = *(const short8*)&Bh[fr * 40 + fq * 8];
    short8 Tl = *(const short8*)&Bl[fr * 40 + fq * 8];
    floatx4 zd = {};
    zd = __builtin_amdgcn_mfma_f32_16x16x32_bf16(Zh, Th, zd, 0, 0, 0);
    zd = __builtin_amdgcn_mfma_f32_16x16x32_bf16(Zh, Tl, zd, 0, 0, 0);
    zd = __builtin_amdgcn_mfma_f32_16x16x32_bf16(Zl, Th, zd, 0, 0, 0);
    if (it < iters - 1) {
      floatx4 yn = {};
      yn = __builtin_amdgcn_mfma_f32_16x16x32_bf16(Yh, Th, yn, 0, 0, 0);
      yn = __builtin_amdgcn_mfma_f32_16x16x32_bf16(Yh, Tl, yn, 0, 0, 0);
      yn = __builtin_amdgcn_mfma_f32_16x16x32_bf16(Yl, Th, yn, 0, 0, 0);
      split_wr(Bh, Bl, fr, fq, yn);
      asm volatile("" ::: "memory");
      Yh = *(const short8*)&Bh[fr * 40 + fq * 8];
      Yl = *(const short8*)&Bl[fr * 40 + fq * 8];
    }
    split_wr(Bh, Bl, fr, fq, zd);
    asm volatile("" ::: "memory");
    Zh = *(const short8*)&Bh[fr * 40 + fq * 8];
    Zl = *(const short8*)&Bl[fr * 40 + fq * 8];
  }

  // ---- U = (v*sqrt(gf)) * Z via 4 chunks x 3 MFMA
  const float us = sqrtf(gf);
  asm volatile("" ::: "memory");
  ushort* Ah = POOL;           // [64][40] bf16 hi, cols 16..31 zero
  ushort* Al = POOL + 2560;    // lo
  {
    union { ushort u[16]; uint4 q4[2]; } rh, rl;
#pragma unroll
    for (int j = 0; j < 16; ++j) {
      const float x = v[j] * us;
      __hip_bfloat16 hb = __float2bfloat16(x);
      const float hf = __bfloat162float(hb);
      __hip_bfloat16 lb = __float2bfloat16(x - hf);
      rh.u[j] = *(const ushort*)&hb;
      rl.u[j] = *(const ushort*)&lb;
    }
    *(uint4*)&Ah[lane * 40]      = rh.q4[0];
    *(uint4*)&Ah[lane * 40 + 8]  = rh.q4[1];
    *(uint4*)&Al[lane * 40]      = rl.q4[0];
    *(uint4*)&Al[lane * 40 + 8]  = rl.q4[1];
    const uint4 zz = make_uint4(0u, 0u, 0u, 0u);
    *(uint4*)&Ah[lane * 40 + 16] = zz; *(uint4*)&Ah[lane * 40 + 24] = zz;
    *(uint4*)&Al[lane * 40 + 16] = zz; *(uint4*)&Al[lane * 40 + 24] = zz;
  }
  asm volatile("" ::: "memory");
  short8 ah[4], al[4];
#pragma unroll
  for (int m4 = 0; m4 < 4; ++m4) {
    ah[m4] = *(const short8*)&Ah[(m4 * 16 + fr) * 40 + fq * 8];
    al[m4] = *(const short8*)&Al[(m4 * 16 + fr) * 40 + fq * 8];
  }
  floatx4 um[4];
#pragma unroll
  for (int m4 = 0; m4 < 4; ++m4) {
    floatx4 a = {};
    a = __builtin_amdgcn_mfma_f32_16x16x32_bf16(ah[m4], Zh, a, 0, 0, 0);
    a = __builtin_amdgcn_mfma_f32_16x16x32_bf16(ah[m4], Zl, a, 0, 0, 0);
    a = __builtin_amdgcn_mfma_f32_16x16x32_bf16(al[m4], Zh, a, 0, 0, 0);
    um[m4] = a;
  }
  asm volatile("" ::: "memory");
  float* Ub = (float*)POOL;            // [64][20] f32
#pragma unroll
  for (int m4 = 0; m4 < 4; ++m4)
#pragma unroll
    for (int j = 0; j < 4; ++j)
      Ub[(m4 * 16 + fq * 4 + j) * 20 + fr] = um[m4][j];
  asm volatile("" ::: "memory");
  float up[16];
#pragma unroll
  for (int i = 0; i < 4; ++i) {
    const float4 t4 = *(const float4*)&Ub[lane * 20 + i * 4];
    up[i*4+0]=t4.x; up[i*4+1]=t4.y; up[i*4+2]=t4.z; up[i*4+3]=t4.w;
  }
  float* dst = Xg + (size_t)row * DD + lane * 16;
#pragma unroll
  for (int q = 0; q < 4; ++q)
    *(float4*)(dst + q*4) = make_float4(up[q*4], up[q*4+1], up[q*4+2], up[q*4+3]);
  union { __hip_bfloat16 hh[16]; uint4 u[2]; } pk;
#pragma unroll
  for (int j = 0; j < 16; ++j) pk.hh[j] = __float2bfloat16(up[j]);
  uint4* sd = (uint4*)(stage + ((size_t)layer * NROWS + row) * DD + lane * 16);
  sd[0] = pk.u[0]; sd[1] = pk.u[1];
}

// ---------------------------------------------------------------- tail (transpose + classify fused)
// blocks 0..12287: stage (l,row,d) bf16 -> out (row,d,l) fp32
// blocks 12288..13311: Z = U @ S @ V^T; logits = Z @ Wc^T + bc; softmax
// Independent inputs/outputs -> fusing lets the two phases overlap on the GPU.
__global__ __launch_bounds__(256) void tail_kernel(
    const __hip_bfloat16* __restrict__ stage, float* __restrict__ outT,
    const float* __restrict__ X, const float* __restrict__ Wc,
    const float* __restrict__ bc, float* __restrict__ out)
{
  __shared__ __align__(16) float pool[7680];   // 30720 B (max of both paths)
  const int t = threadIdx.x;

  if (blockIdx.x < 12288) {                    // ---- transpose path
    float* buf = pool;                         // [256][18]
    const int row = blockIdx.x >> 2;           // 0..3071
    const int d0  = (blockIdx.x & 3) * 256;
    for (int l = 0; l < NLAY; ++l)
      buf[t * 18 + l] = __bfloat162float(stage[((size_t)l * NROWS + row) * DD + d0 + t]);
    __syncthreads();
    const size_t ob = (size_t)(row * DD + d0) * NLAY;
    for (int i = 0; i < NLAY; ++i) {
      const int idx = i * 256 + t;             // < 4352
      const int dd = idx / 17, ll = idx % 17;
      outT[ob + idx] = buf[dd * 18 + ll];
    }
    return;
  }

  // ---- classify path
  const int b = blockIdx.x - 12288;
  float* U = pool;               // 64*17
  float* S = U + 1088;           // 16*17
  float* V = S + 272;            // 64*17
  float* T = V + 1088;           // 64*17
  float* Z = T + 1088;           // 4096
  float* wsum = Z + 4096;        // 40
  const float* x0 = X + (size_t)(b*3+0) * DD;
  const float* x1 = X + (size_t)(b*3+1) * DD;
  const float* x2 = X + (size_t)(b*3+2) * DD;
  for (int e = t; e < 1024; e += 256) {
    const int i = e >> 4, j = e & 15;
    U[i*17+j] = x0[e];
    V[i*17+j] = x2[e];
  }
  { const int i = t >> 4, j = t & 15; if (t < 256) S[i*17+j] = x1[i*16+j]; }
  __syncthreads();
  for (int e = t; e < 1024; e += 256) {     // T = U @ S
    const int i = e >> 4, j = e & 15;
    float a = 0.f;
    for (int k = 0; k < 16; ++k) a = fmaf(U[i*17+k], S[k*17+j], a);
    T[i*17+j] = a;
  }
  __syncthreads();
  for (int e = t; e < 4096; e += 256) {     // Z = T @ V^T
    const int i = e >> 6, j = e & 63;
    float a = 0.f;
    for (int k = 0; k < 16; ++k) a = fmaf(T[i*17+k], V[j*17+k], a);
    Z[e] = a;
  }
  __syncthreads();
  float part[10] = {};
  for (int e = t; e < 4096; e += 256) {
    const float z = Z[e];
#pragma unroll
    for (int n = 0; n < 10; ++n) part[n] = fmaf(z, Wc[(size_t)n * 4096 + e], part[n]);
  }
#pragma unroll
  for (int n = 0; n < 10; ++n) {
#pragma unroll
    for (int off = 32; off > 0; off >>= 1) part[n] += __shfl_xor(part[n], off, 64);
  }
  if ((t & 63) == 0) {
#pragma unroll
    for (int n = 0; n < 10; ++n) wsum[(t >> 6) * 10 + n] = part[n];
  }
  __syncthreads();
  if (t == 0) {
    float logits[10];
#pragma unroll
    for (int n = 0; n < 10; ++n)
      logits[n] = wsum[0*10+n] + wsum[1*10+n] + wsum[2*10+n] + wsum[3*10+n] + bc[n];
    float mx = logits[0];
    for (int n = 1; n < 10; ++n) mx = fmaxf(mx, logits[n]);
    float ex[10], sm = 0.f;
    for (int n = 0; n < 10; ++n) { ex[n] = expf(logits[n] - mx); sm += ex[n]; }
    const float inv = 1.f / sm;
    for (int n = 0; n < 10; ++n) {
      out[b*10 + n] = ex[n] * inv;
      out[10240 + b*10 + n] = logits[n];
    }
  }
}

// ---------------------------------------------------------------- launch
extern "C" void kernel_launch(void* const* d_in, const int* in_sizes, int n_in,
                              void* d_out, int out_size, void* d_ws, size_t ws_size,
                              hipStream_t stream) {
  const float* Xin = (const float*)d_in[0];
  const float* hp  = (const float*)d_in[1];
  const float* W0  = (const float*)d_in[2];
  const float* Ws  = (const float*)d_in[3];
  const float* bs  = (const float*)d_in[4];
  const float* Wc  = (const float*)d_in[5];
  const float* bc  = (const float*)d_in[6];
  float* out = (float*)d_out;

  char* ws = (char*)d_ws;
  float* Xb = (float*)ws;
  float* Yb = Xb + (size_t)NROWS * DD;
  __hip_bfloat16* stage =
      (__hip_bfloat16*)(ws + 2 * (size_t)NROWS * DD * 4);
  ushort* X0bf = (ushort*)(ws + 2 * (size_t)NROWS * DD * 4
                              + (size_t)NLAY * NROWS * DD * 2);
  ushort* Wbf  = X0bf + (size_t)NROWS * DD;

  convprep_kernel<<<20480, 256, 0, stream>>>(W0, Ws, Wbf, Xin, X0bf);

  gemm_kernel<<<768, 256, 0, stream>>>(X0bf, Wbf, Xb, bs, hp, Yb, 0);
  proj_kernel<<<3072, 64, 0, stream>>>(Yb, Xb, stage, 0, 13);

  for (int l = 0; l < 16; ++l) {
    gemm_kernel<<<768, 256, 0, stream>>>(
        (const ushort*)(stage + (size_t)l * NROWS * DD),
        Wbf + (size_t)(l + 1) * DD * DD,
        Xb, bs + (size_t)l * DD, hp, Yb, 1);
    proj_kernel<<<3072, 64, 0, stream>>>(Yb, Xb, stage, l + 1, 9);
  }

  tail_kernel<<<13312, 256, 0, stream>>>(stage, out + 20480, Xb, Wc, bc, out);
}